// Round 1
// baseline (511.598 us; speedup 1.0000x reference)
//
#include <hip/hip_runtime.h>

#define Bn 64
#define Tn 512
#define En 2048
#define Kn 32
#define Mn (Bn*Tn)          // 32768 rows
#define LOG2E 1.4426950408889634f
#define LN2   0.6931471805599453f

typedef __attribute__((ext_vector_type(8))) short short8;
typedef __attribute__((ext_vector_type(4))) float floatx4;

__device__ inline unsigned int pack_bf16(float a, float b) {
    unsigned int ua = __float_as_uint(a), ub = __float_as_uint(b);
    return ((ua + 0x8000u) >> 16) | (((ub + 0x8000u) & 0xFFFF0000u));
}

// ---------------- prep: W (fp32 [E][K]) -> Wt (bf16 [K][E]), zero out ----------------
__global__ __launch_bounds__(256) void prep_kernel(const float* __restrict__ W,
                                                   unsigned short* __restrict__ Wt,
                                                   float* __restrict__ out) {
    int idx = blockIdx.x * 256 + threadIdx.x;      // 65536 total
    int k = idx >> 11, e = idx & 2047;
    float w = W[e * Kn + k];
    Wt[idx] = (unsigned short)((__float_as_uint(w) + 0x8000u) >> 16);
    if (idx == 0) out[0] = 0.f;
}

// ---------------- GEMM: logits2[m][k] = (X@W + b)[m][k] * LOG2E ----------------
// block: 256 thr (4 waves), 64 rows per block, E-chunks of 64
__global__ __launch_bounds__(256) void gemm_kernel(const float* __restrict__ X,
                                                   const float* __restrict__ bias,
                                                   const unsigned short* __restrict__ Wt,
                                                   float* __restrict__ logits2) {
    __shared__ unsigned short As[64][72];   // [row][e] bf16, pad 8 -> conflict-free b128
    __shared__ unsigned short Bs[32][72];   // [n][e]  bf16 (W^T)

    const int tid  = threadIdx.x;
    const int wave = tid >> 6;
    const int lane = tid & 63;
    const int ml   = lane & 15;             // m (and n) within 16-tile
    const int quad = lane >> 4;             // k-quad
    const int row0 = blockIdx.x * 64;

    floatx4 acc0 = {0.f,0.f,0.f,0.f};
    floatx4 acc1 = {0.f,0.f,0.f,0.f};

    for (int ec = 0; ec < En / 64; ++ec) {
        const int e0 = ec * 64;
        // -- global loads into regs (overlap with previous compute) --
        float4 xr[4];
        #pragma unroll
        for (int i = 0; i < 4; ++i) {
            int flat = tid + i * 256;                 // 0..1023
            int r = flat >> 4, q = flat & 15;
            xr[i] = *(const float4*)&X[(size_t)(row0 + r) * En + e0 + q * 4];
        }
        // W chunk: 32 rows x 64 bf16 = 32x128B; 256 thr x 16B
        int wrow = tid >> 3, wseg = tid & 7;
        uint4 wr = *(const uint4*)&Wt[wrow * En + e0 + wseg * 8];

        __syncthreads();   // previous compute done before LDS overwrite
        #pragma unroll
        for (int i = 0; i < 4; ++i) {
            int flat = tid + i * 256;
            int r = flat >> 4, q = flat & 15;
            uint2 p; p.x = pack_bf16(xr[i].x, xr[i].y); p.y = pack_bf16(xr[i].z, xr[i].w);
            *(uint2*)&As[r][q * 4] = p;
        }
        *(uint4*)&Bs[wrow][wseg * 8] = wr;
        __syncthreads();

        // -- MFMA: 1 m-tile per wave, 2 n-tiles, 2 k-steps --
        #pragma unroll
        for (int kk = 0; kk < 2; ++kk) {
            short8 a  = *(const short8*)&As[wave * 16 + ml][kk * 32 + quad * 8];
            short8 b0 = *(const short8*)&Bs[ml][kk * 32 + quad * 8];
            short8 b1 = *(const short8*)&Bs[16 + ml][kk * 32 + quad * 8];
            acc0 = __builtin_amdgcn_mfma_f32_16x16x32_bf16(a, b0, acc0, 0, 0, 0);
            acc1 = __builtin_amdgcn_mfma_f32_16x16x32_bf16(a, b1, acc1, 0, 0, 0);
        }
    }

    // epilogue: C row = quad*4 + reg, col = lane&15 (+16 for acc1)
    const float bc0 = bias[ml], bc1 = bias[16 + ml];
    const int gr = row0 + wave * 16 + quad * 4;
    #pragma unroll
    for (int r = 0; r < 4; ++r) {
        logits2[(size_t)(gr + r) * Kn + ml]      = (acc0[r] + bc0) * LOG2E;
        logits2[(size_t)(gr + r) * Kn + 16 + ml] = (acc1[r] + bc1) * LOG2E;
    }
}

// ---------------- CRF: one wave per batch ----------------
__global__ __launch_bounds__(64) void crf_kernel(const float* __restrict__ logits2,
                                                 const int* __restrict__ y,
                                                 const void* __restrict__ maskp,
                                                 const float* __restrict__ trans,
                                                 const float* __restrict__ start,
                                                 const float* __restrict__ endt,
                                                 float* __restrict__ out) {
    const int b    = blockIdx.x;
    const int lane = threadIdx.x;
    const int j    = lane & 31;
    const int ibase = (lane >> 5) * 16;     // i-half: [ibase, ibase+16)

    // ---- mask representation detect + length ----
    unsigned int first = *(const unsigned int*)maskp;
    int mode;                                // 0=int32, 1=uint8, 2=float32
    if (first <= 1u) mode = 0;
    else if (first == 0x3F800000u) mode = 2;
    else mode = 1;

    int len = 0;
    if (mode == 0) {
        const int* mb = (const int*)maskp + b * Tn;
        for (int t = lane; t < Tn; t += 64) len += (mb[t] != 0);
    } else if (mode == 1) {
        const unsigned char* mb = (const unsigned char*)maskp + b * Tn;
        for (int t = lane; t < Tn; t += 64) len += (mb[t] != 0);
    } else {
        const float* mb = (const float*)maskp + b * Tn;
        for (int t = lane; t < Tn; t += 64) len += (mb[t] != 0.f);
    }
    #pragma unroll
    for (int o = 32; o; o >>= 1) len += __shfl_xor(len, o, 64);

    // ---- numerator (log2-scaled) ----
    const int* yb = y + b * Tn;
    float num2 = 0.f;
    for (int t = lane; t < Tn; t += 64) {
        if (t < len) {
            int yt = yb[t];
            num2 += logits2[((size_t)b * Tn + t) * Kn + yt];
            if (t >= 1) num2 += trans[yb[t - 1] * Kn + yt] * LOG2E;
        }
    }
    if (lane == 0) num2 += (start[yb[0]] + endt[yb[len - 1]]) * LOG2E;
    #pragma unroll
    for (int o = 32; o; o >>= 1) num2 += __shfl_xor(num2, o, 64);

    // ---- constant P column: P[i][j] = e^{trans[i][j]} ----
    float P[16];
    #pragma unroll
    for (int k = 0; k < 16; ++k)
        P[k] = __builtin_exp2f(trans[(ibase + k) * Kn + j] * LOG2E);

    // ---- forward recursion in log2 space ----
    const float* xrow = logits2 + (size_t)b * Tn * Kn;
    float a = start[j] * LOG2E + xrow[j];    // alpha2_0
    float S = __shfl(a, 0, 64);
    a -= S;

    float xn = xrow[Kn + j];                 // prefetch t=1
    for (int t = 1; t < len; ++t) {
        float xcur = xn;
        int tn = t + 1 < Tn ? t + 1 : Tn - 1;
        xn = xrow[tn * Kn + j];

        float u = __builtin_exp2f(a);
        float w0 = 0.f, w1 = 0.f, w2 = 0.f, w3 = 0.f;
        #pragma unroll
        for (int k = 0; k < 16; k += 4) {
            float u0 = __shfl(u, ibase + k,     64);
            float u1 = __shfl(u, ibase + k + 1, 64);
            float u2 = __shfl(u, ibase + k + 2, 64);
            float u3 = __shfl(u, ibase + k + 3, 64);
            w0 = fmaf(u0, P[k],     w0);
            w1 = fmaf(u1, P[k + 1], w1);
            w2 = fmaf(u2, P[k + 2], w2);
            w3 = fmaf(u3, P[k + 3], w3);
        }
        float w = (w0 + w1) + (w2 + w3);
        w += __shfl_xor(w, 32, 64);          // combine i-halves
        float n = xcur + __builtin_log2f(w);
        if ((t & 3) == 0) {                  // renormalize every 4 steps
            float sg = __shfl(n, 0, 64);
            a = n - sg;
            S += sg;
        } else {
            a = n;
        }
    }

    // ---- denominator finish ----
    float v = (lane < 32) ? __builtin_exp2f(a + endt[j] * LOG2E) : 0.f;
    #pragma unroll
    for (int o = 32; o; o >>= 1) v += __shfl_xor(v, o, 64);
    float den2 = S + __builtin_log2f(v);

    if (lane == 0) atomicAdd(out, (den2 - num2) * LN2);
}

extern "C" void kernel_launch(void* const* d_in, const int* in_sizes, int n_in,
                              void* d_out, int out_size, void* d_ws, size_t ws_size,
                              hipStream_t stream) {
    const float* X     = (const float*)d_in[0];
    const int*   y     = (const int*)  d_in[1];
    const void*  mask  =               d_in[2];
    const float* W     = (const float*)d_in[3];
    const float* bias  = (const float*)d_in[4];
    const float* trans = (const float*)d_in[5];
    const float* start = (const float*)d_in[6];
    const float* endt  = (const float*)d_in[7];
    float* out = (float*)d_out;

    float* logits2 = (float*)d_ws;                                   // 4 MB
    unsigned short* Wt = (unsigned short*)((char*)d_ws + (size_t)Mn * Kn * 4);  // 128 KB

    prep_kernel<<<256, 256, 0, stream>>>(W, Wt, out);
    gemm_kernel<<<Mn / 64, 256, 0, stream>>>(X, bias, Wt, logits2);
    crf_kernel<<<Bn, 64, 0, stream>>>(logits2, y, mask, trans, start, endt, out);
}

// Round 2
// 466.654 us; speedup vs baseline: 1.0963x; 1.0963x over previous
//
#include <hip/hip_runtime.h>

#define Bn 64
#define Tn 512
#define En 2048
#define Kn 32
#define Mn (Bn*Tn)          // 32768 rows
#define LOG2E 1.4426950408889634f
#define LN2   0.6931471805599453f

typedef __attribute__((ext_vector_type(8))) short short8;
typedef __attribute__((ext_vector_type(4))) float floatx4;

__device__ inline unsigned int pack_bf16(float a, float b) {
    unsigned int ua = __float_as_uint(a), ub = __float_as_uint(b);
    return ((ua + 0x8000u) >> 16) | (((ub + 0x8000u) & 0xFFFF0000u));
}

__device__ inline float rdlane(float v, int l) {
    return __uint_as_float(__builtin_amdgcn_readlane(__float_as_uint(v), l));
}

// ---------------- prep: W (fp32 [E][K]) -> Wt (bf16 [K][E]), zero out ----------------
__global__ __launch_bounds__(256) void prep_kernel(const float* __restrict__ W,
                                                   unsigned short* __restrict__ Wt,
                                                   float* __restrict__ out) {
    int idx = blockIdx.x * 256 + threadIdx.x;      // 65536 total
    int k = idx >> 11, e = idx & 2047;
    float w = W[e * Kn + k];
    Wt[idx] = (unsigned short)((__float_as_uint(w) + 0x8000u) >> 16);
    if (idx == 0) out[0] = 0.f;
}

// ---------------- GEMM v2: barrier-free, LDS-free streaming ----------------
// 512 blocks x 256 thr (4 waves). Each wave owns 16 rows; A-fragments loaded
// straight from global in MFMA A-layout; B-fragments from L2-resident Wt.
__global__ __launch_bounds__(256) void gemm_kernel(const float* __restrict__ X,
                                                   const float* __restrict__ bias,
                                                   const unsigned short* __restrict__ Wt,
                                                   float* __restrict__ logits2) {
    const int tid  = threadIdx.x;
    const int wave = tid >> 6;
    const int lane = tid & 63;
    const int ml   = lane & 15;
    const int quad = lane >> 4;
    const int row0 = blockIdx.x * 64;

    const float*          xp  = X  + (size_t)(row0 + wave * 16 + ml) * En + quad * 8;
    const unsigned short* b0p = Wt + ml * En        + quad * 8;
    const unsigned short* b1p = Wt + (16 + ml) * En + quad * 8;

    floatx4 acc0 = {0.f,0.f,0.f,0.f};
    floatx4 acc1 = {0.f,0.f,0.f,0.f};

    #pragma unroll 4
    for (int e0 = 0; e0 < En; e0 += 32) {
        float4 xa = *(const float4*)(xp + e0);
        float4 xb = *(const float4*)(xp + e0 + 4);
        short8 b0 = *(const short8*)(b0p + e0);
        short8 b1 = *(const short8*)(b1p + e0);
        union { unsigned int u[4]; short8 s; } av;
        av.u[0] = pack_bf16(xa.x, xa.y);
        av.u[1] = pack_bf16(xa.z, xa.w);
        av.u[2] = pack_bf16(xb.x, xb.y);
        av.u[3] = pack_bf16(xb.z, xb.w);
        acc0 = __builtin_amdgcn_mfma_f32_16x16x32_bf16(av.s, b0, acc0, 0, 0, 0);
        acc1 = __builtin_amdgcn_mfma_f32_16x16x32_bf16(av.s, b1, acc1, 0, 0, 0);
    }

    // epilogue: C row = quad*4 + reg, col = lane&15 (+16 for acc1)  [verified R1]
    const float bc0 = bias[ml], bc1 = bias[16 + ml];
    const int gr = row0 + wave * 16 + quad * 4;
    #pragma unroll
    for (int r = 0; r < 4; ++r) {
        logits2[(size_t)(gr + r) * Kn + ml]      = (acc0[r] + bc0) * LOG2E;
        logits2[(size_t)(gr + r) * Kn + 16 + ml] = (acc1[r] + bc1) * LOG2E;
    }
}

// ---------------- CRF v2: one wave per batch, readlane broadcast ----------------
__global__ __launch_bounds__(64) void crf_kernel(const float* __restrict__ logits2,
                                                 const int* __restrict__ y,
                                                 const void* __restrict__ maskp,
                                                 const float* __restrict__ trans,
                                                 const float* __restrict__ start,
                                                 const float* __restrict__ endt,
                                                 float* __restrict__ out) {
    const int b    = blockIdx.x;
    const int lane = threadIdx.x;
    const int j    = lane & 31;           // lanes 32..63 duplicate state j

    // ---- mask representation detect + length ----
    unsigned int first = *(const unsigned int*)maskp;
    int mode;                              // 0=int32, 1=uint8, 2=float32
    if (first <= 1u) mode = 0;
    else if (first == 0x3F800000u) mode = 2;
    else mode = 1;

    int len = 0;
    if (mode == 0) {
        const int* mb = (const int*)maskp + b * Tn;
        for (int t = lane; t < Tn; t += 64) len += (mb[t] != 0);
    } else if (mode == 1) {
        const unsigned char* mb = (const unsigned char*)maskp + b * Tn;
        for (int t = lane; t < Tn; t += 64) len += (mb[t] != 0);
    } else {
        const float* mb = (const float*)maskp + b * Tn;
        for (int t = lane; t < Tn; t += 64) len += (mb[t] != 0.f);
    }
    #pragma unroll
    for (int o = 32; o; o >>= 1) len += __shfl_xor(len, o, 64);

    // ---- numerator (log2-scaled) ----
    const int* yb = y + b * Tn;
    float num2 = 0.f;
    for (int t = lane; t < Tn; t += 64) {
        if (t < len) {
            int yt = yb[t];
            num2 += logits2[((size_t)b * Tn + t) * Kn + yt];
            if (t >= 1) num2 += trans[yb[t - 1] * Kn + yt] * LOG2E;
        }
    }
    if (lane == 0) num2 += (start[yb[0]] + endt[yb[len - 1]]) * LOG2E;
    #pragma unroll
    for (int o = 32; o; o >>= 1) num2 += __shfl_xor(num2, o, 64);

    // ---- P column: P[i] = e^{trans[i][j]} (full 32 sources per lane) ----
    float P[32];
    #pragma unroll
    for (int i = 0; i < 32; ++i)
        P[i] = __builtin_exp2f(trans[i * Kn + j] * LOG2E);

    // ---- forward recursion in log2 space ----
    const float* xrow = logits2 + (size_t)b * Tn * Kn;
    float a = start[j] * LOG2E + xrow[j];
    float S = 0.f;

    float cur[4], nxt[4];
    #pragma unroll
    for (int q = 0; q < 4; ++q) {
        int tq = 1 + q; if (tq > Tn - 1) tq = Tn - 1;
        cur[q] = xrow[tq * Kn + j];
    }

    for (int g = 1; g < len; g += 4) {
        #pragma unroll
        for (int q = 0; q < 4; ++q) {             // prefetch next group (lead ~600 cyc)
            int tq = g + 4 + q; if (tq > Tn - 1) tq = Tn - 1;
            nxt[q] = xrow[tq * Kn + j];
        }
        #pragma unroll
        for (int q = 0; q < 4; ++q) {
            if (g + q < len) {
                float u = __builtin_exp2f(a);
                float w0 = 0.f, w1 = 0.f, w2 = 0.f, w3 = 0.f;
                #pragma unroll
                for (int i = 0; i < 32; i += 4) {
                    float s0 = rdlane(u, i);
                    float s1 = rdlane(u, i + 1);
                    float s2 = rdlane(u, i + 2);
                    float s3 = rdlane(u, i + 3);
                    w0 = fmaf(s0, P[i],     w0);
                    w1 = fmaf(s1, P[i + 1], w1);
                    w2 = fmaf(s2, P[i + 2], w2);
                    w3 = fmaf(s3, P[i + 3], w3);
                }
                float w = (w0 + w1) + (w2 + w3);
                float n = cur[q] + __builtin_log2f(w);
                if (q == 3) {                      // renorm once per group
                    float sg = rdlane(n, 0);
                    a = n - sg;
                    S += sg;
                } else {
                    a = n;
                }
            }
        }
        #pragma unroll
        for (int q = 0; q < 4; ++q) cur[q] = nxt[q];
    }

    // ---- denominator finish ----
    float v = (lane < 32) ? __builtin_exp2f(a + endt[j] * LOG2E) : 0.f;
    #pragma unroll
    for (int o = 32; o; o >>= 1) v += __shfl_xor(v, o, 64);
    float den2 = S + __builtin_log2f(v);

    if (lane == 0) atomicAdd(out, (den2 - num2) * LN2);
}

extern "C" void kernel_launch(void* const* d_in, const int* in_sizes, int n_in,
                              void* d_out, int out_size, void* d_ws, size_t ws_size,
                              hipStream_t stream) {
    const float* X     = (const float*)d_in[0];
    const int*   y     = (const int*)  d_in[1];
    const void*  mask  =               d_in[2];
    const float* W     = (const float*)d_in[3];
    const float* bias  = (const float*)d_in[4];
    const float* trans = (const float*)d_in[5];
    const float* start = (const float*)d_in[6];
    const float* endt  = (const float*)d_in[7];
    float* out = (float*)d_out;

    float* logits2 = (float*)d_ws;                                              // 4 MB
    unsigned short* Wt = (unsigned short*)((char*)d_ws + (size_t)Mn * Kn * 4);  // 128 KB

    prep_kernel<<<256, 256, 0, stream>>>(W, Wt, out);
    gemm_kernel<<<Mn / 64, 256, 0, stream>>>(X, bias, Wt, logits2);
    crf_kernel<<<Bn, 64, 0, stream>>>(logits2, y, mask, trans, start, endt, out);
}

// Round 3
// 431.926 us; speedup vs baseline: 1.1845x; 1.0804x over previous
//
#include <hip/hip_runtime.h>

#define Bn 64
#define Tn 512
#define En 2048
#define Kn 32
#define Mn (Bn*Tn)          // 32768 rows
#define LOG2E 1.4426950408889634f
#define LN2   0.6931471805599453f
#define NSEG 8
#define SEGLEN 64

typedef __attribute__((ext_vector_type(8)))  short short8;
typedef __attribute__((ext_vector_type(4)))  float floatx4;
typedef __attribute__((ext_vector_type(16))) float floatx16;

__device__ inline unsigned int pack_bf16(float a, float b) {
    unsigned int ua = __float_as_uint(a), ub = __float_as_uint(b);
    return ((ua + 0x8000u) >> 16) | (((ub + 0x8000u) & 0xFFFF0000u));
}
// truncation pack: (hi<<16)|hi16(lo)  (3 VALU; RNE not needed at this error budget)
__device__ inline unsigned int pack_trunc(float lo, float hi) {
    return (__float_as_uint(lo) >> 16) | (__float_as_uint(hi) & 0xFFFF0000u);
}
__device__ inline float rdlane(float v, int l) {
    return __uint_as_float(__builtin_amdgcn_readlane(__float_as_uint(v), l));
}

// ---------------- prep: W (fp32 [E][K]) -> Wt (bf16 [K][E]), zero out ----------------
__global__ __launch_bounds__(256) void prep_kernel(const float* __restrict__ W,
                                                   unsigned short* __restrict__ Wt,
                                                   float* __restrict__ out) {
    int idx = blockIdx.x * 256 + threadIdx.x;      // 65536 total
    int k = idx >> 11, e = idx & 2047;
    float w = W[e * Kn + k];
    Wt[idx] = (unsigned short)((__float_as_uint(w) + 0x8000u) >> 16);
    if (idx == 0) out[0] = 0.f;
}

// ---------------- GEMM: barrier-free, LDS-free streaming ----------------
__global__ __launch_bounds__(256) void gemm_kernel(const float* __restrict__ X,
                                                   const float* __restrict__ bias,
                                                   const unsigned short* __restrict__ Wt,
                                                   float* __restrict__ logits2) {
    const int tid  = threadIdx.x;
    const int wave = tid >> 6;
    const int lane = tid & 63;
    const int ml   = lane & 15;
    const int quad = lane >> 4;
    const int row0 = blockIdx.x * 64;

    const float*          xp  = X  + (size_t)(row0 + wave * 16 + ml) * En + quad * 8;
    const unsigned short* b0p = Wt + ml * En        + quad * 8;
    const unsigned short* b1p = Wt + (16 + ml) * En + quad * 8;

    floatx4 acc0 = {0.f,0.f,0.f,0.f};
    floatx4 acc1 = {0.f,0.f,0.f,0.f};

    #pragma unroll 8
    for (int e0 = 0; e0 < En; e0 += 32) {
        float4 xa = *(const float4*)(xp + e0);
        float4 xb = *(const float4*)(xp + e0 + 4);
        short8 b0 = *(const short8*)(b0p + e0);
        short8 b1 = *(const short8*)(b1p + e0);
        union { unsigned int u[4]; short8 s; } av;
        av.u[0] = pack_bf16(xa.x, xa.y);
        av.u[1] = pack_bf16(xa.z, xa.w);
        av.u[2] = pack_bf16(xb.x, xb.y);
        av.u[3] = pack_bf16(xb.z, xb.w);
        acc0 = __builtin_amdgcn_mfma_f32_16x16x32_bf16(av.s, b0, acc0, 0, 0, 0);
        acc1 = __builtin_amdgcn_mfma_f32_16x16x32_bf16(av.s, b1, acc1, 0, 0, 0);
    }

    const float bc0 = bias[ml], bc1 = bias[16 + ml];
    const int gr = row0 + wave * 16 + quad * 4;
    #pragma unroll
    for (int r = 0; r < 4; ++r) {
        logits2[(size_t)(gr + r) * Kn + ml]      = (acc0[r] + bc0) * LOG2E;
        logits2[(size_t)(gr + r) * Kn + 16 + ml] = (acc1[r] + bc1) * LOG2E;
    }
}

__device__ inline int seq_len(const void* maskp, int b, int lane) {
    unsigned int first = *(const unsigned int*)maskp;
    int mode = (first <= 1u) ? 0 : (first == 0x3F800000u ? 2 : 1);
    int len = 0;
    if (mode == 0) {
        const int* mb = (const int*)maskp + b * Tn;
        for (int t = lane; t < Tn; t += 64) len += (mb[t] != 0);
    } else if (mode == 1) {
        const unsigned char* mb = (const unsigned char*)maskp + b * Tn;
        for (int t = lane; t < Tn; t += 64) len += (mb[t] != 0);
    } else {
        const float* mb = (const float*)maskp + b * Tn;
        for (int t = lane; t < Tn; t += 64) len += (mb[t] != 0.f);
    }
    #pragma unroll
    for (int o = 32; o; o >>= 1) len += __shfl_xor(len, o, 64);
    return len;
}

// ---------------- CRF phase A: per-(batch,segment) 32x32 transfer product ----------------
// H_s = (M_a @ ... @ M_b)^T built as H' = diag(e_t) P^T H via 2x mfma_32x32x16_bf16.
// A-layout: row m = lane&31 (=j), k = (lane>>5)*8+i   -> per-lane scalar e[j] row scale.
// B-layout: col n = lane&31, k = (lane>>5)*8+i.
// C-layout: col = lane&31, row = (r&3)+8*(r>>2)+4*(lane>>5)   [m74/m101 verified]
__global__ __launch_bounds__(64) void crf_seg_kernel(const float* __restrict__ logits2,
                                                     const void* __restrict__ maskp,
                                                     const float* __restrict__ trans,
                                                     float* __restrict__ Hs,
                                                     float* __restrict__ Ss) {
    const int bx = blockIdx.x;
    const int b = bx >> 3, s = bx & 7;
    const int lane = threadIdx.x;
    const int j = lane & 31;
    const int h = lane >> 5;

    const int len = seq_len(maskp, b, lane);
    if (s * SEGLEN >= len) return;                    // fully masked: combine skips it too
    const int tstart = (s == 0) ? 1 : s * SEGLEN;
    const int tend   = min(s * SEGLEN + SEGLEN - 1, len - 1);

    // P^T rows for this lane: PT1[i] = exp2(trans2[8h+i][j]), PT2[i] = exp2(trans2[16+8h+i][j])
    float PT1[8], PT2[8];
    #pragma unroll
    for (int i = 0; i < 8; ++i) {
        PT1[i] = __builtin_exp2f(trans[(8 * h + i) * Kn + j] * LOG2E);
        PT2[i] = __builtin_exp2f(trans[(16 + 8 * h + i) * Kn + j] * LOG2E);
    }

    // B fragments <- identity
    union U4 { unsigned int u[4]; short8 v; };
    U4 fb1, fb2;
    #pragma unroll
    for (int p = 0; p < 4; ++p) { fb1.u[p] = 0u; fb2.u[p] = 0u; }
    int i1 = j - 8 * h;                      // frag1 covers k = 8h..8h+7
    if (i1 >= 0 && i1 < 8) fb1.u[i1 >> 1] |= 0x3F80u << (16 * (i1 & 1));
    int i2 = j - 16 - 8 * h;                 // frag2 covers k = 16+8h..16+8h+7
    if (i2 >= 0 && i2 < 8) fb2.u[i2 >> 1] |= 0x3F80u << (16 * (i2 & 1));

    const float* xrow = logits2 + (size_t)b * Tn * Kn + j;
    floatx16 Hc;                              // H in C layout (fp32), valid after >=1 step
    float S = 0.f;
    int stepc = 0;

    float cur[4], nxt[4];
    #pragma unroll
    for (int q = 0; q < 4; ++q) cur[q] = xrow[min(tstart + q, tend) * Kn];

    for (int g = tstart; g <= tend; g += 4) {
        #pragma unroll
        for (int q = 0; q < 4; ++q) nxt[q] = xrow[min(g + 4 + q, tend) * Kn];
        #pragma unroll
        for (int q = 0; q < 4; ++q) {
            if (g + q <= tend) {
                float e = __builtin_exp2f(cur[q]);
                // A = diag(e) P^T, truncate-packed to bf16
                U4 fa1, fa2;
                #pragma unroll
                for (int p = 0; p < 4; ++p) {
                    fa1.u[p] = pack_trunc(e * PT1[2 * p], e * PT1[2 * p + 1]);
                    fa2.u[p] = pack_trunc(e * PT2[2 * p], e * PT2[2 * p + 1]);
                }
                floatx16 acc = {0.f,0.f,0.f,0.f,0.f,0.f,0.f,0.f,
                                0.f,0.f,0.f,0.f,0.f,0.f,0.f,0.f};
                acc = __builtin_amdgcn_mfma_f32_32x32x16_bf16(fa1.v, fb1.v, acc, 0, 0, 0);
                acc = __builtin_amdgcn_mfma_f32_32x32x16_bf16(fa2.v, fb2.v, acc, 0, 0, 0);

                if ((stepc & 7) == 7) {       // renorm every 8 steps (growth <= 2^96)
                    float m = acc[0];
                    #pragma unroll
                    for (int r = 1; r < 16; ++r) m = fmaxf(m, acc[r]);
                    #pragma unroll
                    for (int o = 1; o < 64; o <<= 1) m = fmaxf(m, __shfl_xor(m, o, 64));
                    int eb = (int)((__float_as_uint(m) >> 23) & 0xFF);
                    float scale = __uint_as_float((unsigned int)(254 - eb) << 23);
                    #pragma unroll
                    for (int r = 0; r < 16; ++r) acc[r] *= scale;
                    S += (float)(eb - 127);
                }
                ++stepc;
                Hc = acc;

                // C -> B relayout: pack reg pairs (consecutive rows), exchange with lane^32
                unsigned int w[8], pw[8];
                #pragma unroll
                for (int p = 0; p < 8; ++p) w[p] = pack_trunc(acc[2 * p], acc[2 * p + 1]);
                #pragma unroll
                for (int p = 0; p < 8; ++p) pw[p] = __shfl_xor(w[p], 32, 64);
                if (h == 0) {
                    fb1.u[0] = w[0];  fb1.u[1] = w[1];  fb1.u[2] = pw[0]; fb1.u[3] = pw[1];
                    fb2.u[0] = w[4];  fb2.u[1] = w[5];  fb2.u[2] = pw[4]; fb2.u[3] = pw[5];
                } else {
                    fb1.u[0] = pw[2]; fb1.u[1] = pw[3]; fb1.u[2] = w[2];  fb1.u[3] = w[3];
                    fb2.u[0] = pw[6]; fb2.u[1] = pw[7]; fb2.u[2] = w[6];  fb2.u[3] = w[7];
                }
            }
        }
        #pragma unroll
        for (int q = 0; q < 4; ++q) cur[q] = nxt[q];
    }

    // store H (fp32, C layout -> [row][col]) + log2-scale
    float* hp = Hs + (size_t)(b * 8 + s) * 1024;
    #pragma unroll
    for (int r = 0; r < 16; ++r) {
        int row = (r & 3) + 8 * (r >> 2) + 4 * h;
        hp[row * 32 + j] = Hc[r];
    }
    if (lane == 0) Ss[b * 8 + s] = S;
}

// ---------------- CRF phase B: per-batch combine + numerator ----------------
__global__ __launch_bounds__(64) void crf_comb_kernel(const float* __restrict__ logits2,
                                                      const int* __restrict__ y,
                                                      const void* __restrict__ maskp,
                                                      const float* __restrict__ trans,
                                                      const float* __restrict__ start,
                                                      const float* __restrict__ endt,
                                                      const float* __restrict__ Hs,
                                                      const float* __restrict__ Ss,
                                                      float* __restrict__ out) {
    const int b = blockIdx.x;
    const int lane = threadIdx.x;
    const int j = lane & 31;

    const int len = seq_len(maskp, b, lane);

    // numerator (log2 domain)
    const int* yb = y + b * Tn;
    float num2 = 0.f;
    for (int t = lane; t < Tn; t += 64) {
        if (t < len) {
            int yt = yb[t];
            num2 += logits2[((size_t)b * Tn + t) * Kn + yt];
            if (t >= 1) num2 += trans[yb[t - 1] * Kn + yt] * LOG2E;
        }
    }
    if (lane == 0) num2 += (start[yb[0]] + endt[yb[len - 1]]) * LOG2E;
    #pragma unroll
    for (int o = 32; o; o >>= 1) num2 += __shfl_xor(num2, o, 64);

    // alpha_0 in linear domain with log2 scale S
    float a2 = start[j] * LOG2E + logits2[(size_t)b * Tn * Kn + j];
    float m0 = a2;
    #pragma unroll
    for (int o = 1; o < 64; o <<= 1) m0 = fmaxf(m0, __shfl_xor(m0, o, 64));
    float S = m0;
    float u = __builtin_exp2f(a2 - m0);

    for (int s = 0; s < NSEG; ++s) {
        if (s * SEGLEN >= len) break;
        const float* hrow = Hs + (size_t)(b * 8 + s) * 1024 + j * 32;
        float4 hr[8];
        #pragma unroll
        for (int p = 0; p < 8; ++p) hr[p] = *(const float4*)(hrow + 4 * p);
        float v0 = 0.f, v1 = 0.f, v2 = 0.f, v3 = 0.f;
        #pragma unroll
        for (int p = 0; p < 8; ++p) {
            v0 = fmaf(hr[p].x, rdlane(u, 4 * p),     v0);
            v1 = fmaf(hr[p].y, rdlane(u, 4 * p + 1), v1);
            v2 = fmaf(hr[p].z, rdlane(u, 4 * p + 2), v2);
            v3 = fmaf(hr[p].w, rdlane(u, 4 * p + 3), v3);
        }
        float v = (v0 + v1) + (v2 + v3);
        float mm = v;
        #pragma unroll
        for (int o = 1; o < 64; o <<= 1) mm = fmaxf(mm, __shfl_xor(mm, o, 64));
        int eb = (int)((__float_as_uint(mm) >> 23) & 0xFF);
        u = v * __uint_as_float((unsigned int)(254 - eb) << 23);
        S += (float)(eb - 127) + Ss[b * 8 + s];
    }

    float fv = (lane < 32) ? u * __builtin_exp2f(endt[j] * LOG2E) : 0.f;
    #pragma unroll
    for (int o = 32; o; o >>= 1) fv += __shfl_xor(fv, o, 64);
    float den2 = S + __builtin_log2f(fv);

    if (lane == 0) atomicAdd(out, (den2 - num2) * LN2);
}

extern "C" void kernel_launch(void* const* d_in, const int* in_sizes, int n_in,
                              void* d_out, int out_size, void* d_ws, size_t ws_size,
                              hipStream_t stream) {
    const float* X     = (const float*)d_in[0];
    const int*   y     = (const int*)  d_in[1];
    const void*  mask  =               d_in[2];
    const float* W     = (const float*)d_in[3];
    const float* bias  = (const float*)d_in[4];
    const float* trans = (const float*)d_in[5];
    const float* start = (const float*)d_in[6];
    const float* endt  = (const float*)d_in[7];
    float* out = (float*)d_out;

    char* ws = (char*)d_ws;
    float*          logits2 = (float*)ws;                         ws += (size_t)Mn * Kn * 4;   // 4 MB
    unsigned short* Wt      = (unsigned short*)ws;                ws += (size_t)Kn * En * 2;   // 128 KB
    float*          Hs      = (float*)ws;                         ws += (size_t)Bn * NSEG * 1024 * 4; // 2 MB
    float*          Ss      = (float*)ws;

    prep_kernel<<<256, 256, 0, stream>>>(W, Wt, out);
    gemm_kernel<<<Mn / 64, 256, 0, stream>>>(X, bias, Wt, logits2);
    crf_seg_kernel<<<Bn * NSEG, 64, 0, stream>>>(logits2, mask, trans, Hs, Ss);
    crf_comb_kernel<<<Bn, 64, 0, stream>>>(logits2, y, mask, trans, start, endt, Hs, Ss, out);
}